// Round 6
// baseline (70.147 us; speedup 1.0000x reference)
//
#include <hip/hip_runtime.h>
#include <math.h>

#define CANON_EPS 1e-4f
#define KPT 16  // atoms per thread in the moments pass

// ---------------------------------------------------------------------------
// Kernel 0: zero the 9*G float accumulator region (d_ws is poisoned once,
// never re-poisoned between replays, so we must clear it every launch).
// ---------------------------------------------------------------------------
__global__ __launch_bounds__(256) void zero_ws_kernel(float* __restrict__ wsf,
                                                      int total) {
  int i = (int)(blockIdx.x * (unsigned)blockDim.x + threadIdx.x);
  if (i < total) wsf[i] = 0.0f;
}

// ---------------------------------------------------------------------------
// Kernel A: atom-parallel streaming segmented reduction.
// Thread t owns atoms [t*KPT, t*KPT+KPT): 12 float4 + 4 int4 coalesced loads,
// register-accumulates 9 raw moments per graph-run, flushes with atomicAdd on
// graph change. Also emits wsi[g] = first atom index with batch >= g (each
// entry written exactly once, empty graphs included), wsi[G] = n.
// ---------------------------------------------------------------------------
__global__ __launch_bounds__(256) void moments_kernel(
    const float* __restrict__ pos, const int* __restrict__ batch,
    int* __restrict__ wsi, float* __restrict__ wsf, int n, int G) {
  int t = (int)(blockIdx.x * (unsigned)blockDim.x + threadIdx.x);
  int i0 = t * KPT;
  if (i0 >= n) return;

  int pb = (i0 > 0) ? batch[i0 - 1] : -1;

  float sx = 0.f, sy = 0.f, sz = 0.f;
  float sxx = 0.f, syy = 0.f, szz = 0.f, sxy = 0.f, sxz = 0.f, syz = 0.f;
  int cur = pb;

#define FLUSH()                                                              \
  if (cur >= 0) {                                                            \
    atomicAdd(&wsf[0 * G + cur], sx);                                        \
    atomicAdd(&wsf[1 * G + cur], sy);                                        \
    atomicAdd(&wsf[2 * G + cur], sz);                                        \
    atomicAdd(&wsf[3 * G + cur], sxx);                                       \
    atomicAdd(&wsf[4 * G + cur], syy);                                       \
    atomicAdd(&wsf[5 * G + cur], szz);                                       \
    atomicAdd(&wsf[6 * G + cur], sxy);                                       \
    atomicAdd(&wsf[7 * G + cur], sxz);                                       \
    atomicAdd(&wsf[8 * G + cur], syz);                                       \
  }

  if (i0 + KPT <= n) {
    // ---- fast path: full vector loads ------------------------------------
    int B[KPT];
#pragma unroll
    for (int q = 0; q < KPT / 4; ++q) {
      int4 b4 = *reinterpret_cast<const int4*>(batch + i0 + 4 * q);
      B[4 * q + 0] = b4.x; B[4 * q + 1] = b4.y;
      B[4 * q + 2] = b4.z; B[4 * q + 3] = b4.w;
    }
    float P[3 * KPT];
#pragma unroll
    for (int q = 0; q < 3 * KPT / 4; ++q) {
      float4 p4 = *reinterpret_cast<const float4*>(pos + (size_t)3 * i0 + 4 * q);
      P[4 * q + 0] = p4.x; P[4 * q + 1] = p4.y;
      P[4 * q + 2] = p4.z; P[4 * q + 3] = p4.w;
    }
#pragma unroll
    for (int k = 0; k < KPT; ++k) {
      int bk = B[k];
      if (bk != cur) {
        for (int g = cur + 1; g <= bk; ++g) wsi[g] = i0 + k;
        FLUSH();
        sx = sy = sz = sxx = syy = szz = sxy = sxz = syz = 0.f;
        cur = bk;
      }
      float x = P[3 * k + 0], y = P[3 * k + 1], z = P[3 * k + 2];
      sx += x; sy += y; sz += z;
      sxx = fmaf(x, x, sxx); syy = fmaf(y, y, syy); szz = fmaf(z, z, szz);
      sxy = fmaf(x, y, sxy); sxz = fmaf(x, z, sxz); syz = fmaf(y, z, syz);
    }
  } else {
    // ---- tail path (only the last thread when n % KPT != 0) --------------
    for (int i = i0; i < n; ++i) {
      int bk = batch[i];
      if (bk != cur) {
        for (int g = cur + 1; g <= bk; ++g) wsi[g] = i;
        FLUSH();
        sx = sy = sz = sxx = syy = szz = sxy = sxz = syz = 0.f;
        cur = bk;
      }
      float x = pos[3 * i + 0], y = pos[3 * i + 1], z = pos[3 * i + 2];
      sx += x; sy += y; sz += z;
      sxx = fmaf(x, x, sxx); syy = fmaf(y, y, syy); szz = fmaf(z, z, szz);
      sxy = fmaf(x, y, sxy); sxz = fmaf(x, z, sxz); syz = fmaf(y, z, syz);
    }
  }
  FLUSH();
#undef FLUSH

  // thread containing atom n-1 fills the trailing starts (incl. wsi[G] = n)
  if (i0 + KPT >= n) {
    for (int g = cur + 1; g <= G; ++g) wsi[g] = n;
  }
}

// ---------------------------------------------------------------------------
// Branch-free 3x3 symmetric Jacobi eigensolver in f32, 5 cyclic sweeps.
// Columns of Q = eigenvectors; eigenvalues sorted ascending (matches eigh).
// ---------------------------------------------------------------------------
__device__ __forceinline__ void jacobi3_f32(float a00, float a11, float a22,
                                            float a01, float a02, float a12,
                                            float Q[3][3]) {
  float A00 = a00, A11 = a11, A22 = a22;
  float A01 = a01, A02 = a02, A12 = a12;
  float Q00 = 1.f, Q01 = 0.f, Q02 = 0.f;
  float Q10 = 0.f, Q11 = 1.f, Q12 = 0.f;
  float Q20 = 0.f, Q21 = 0.f, Q22 = 1.f;

#define ROT(App, Aqq, Apq, Akp, Akq, Qrp0, Qrq0, Qrp1, Qrq1, Qrp2, Qrq2)     \
  {                                                                          \
    float apq = Apq;                                                         \
    float theta = (Aqq - App) / (2.0f * apq);                                \
    float t = copysignf(1.0f, theta) /                                       \
              (fabsf(theta) + sqrtf(1.0f + theta * theta));                  \
    t = (apq == 0.0f) ? 0.0f : t; /* kills 0/0 NaN path */                   \
    float c = 1.0f / sqrtf(1.0f + t * t);                                    \
    float s = t * c;                                                         \
    App = App - t * apq;                                                     \
    Aqq = Aqq + t * apq;                                                     \
    Apq = 0.0f;                                                              \
    float akp = Akp, akq = Akq;                                              \
    Akp = c * akp - s * akq;                                                 \
    Akq = s * akp + c * akq;                                                 \
    float r0p = Qrp0, r0q = Qrq0;                                            \
    Qrp0 = c * r0p - s * r0q;                                                \
    Qrq0 = s * r0p + c * r0q;                                                \
    float r1p = Qrp1, r1q = Qrq1;                                            \
    Qrp1 = c * r1p - s * r1q;                                                \
    Qrq1 = s * r1p + c * r1q;                                                \
    float r2p = Qrp2, r2q = Qrq2;                                            \
    Qrp2 = c * r2p - s * r2q;                                                \
    Qrq2 = s * r2p + c * r2q;                                                \
  }

#pragma unroll
  for (int sweep = 0; sweep < 5; ++sweep) {
    ROT(A00, A11, A01, A02, A12, Q00, Q01, Q10, Q11, Q20, Q21);
    ROT(A00, A22, A02, A01, A12, Q00, Q02, Q10, Q12, Q20, Q22);
    ROT(A11, A22, A12, A01, A02, Q01, Q02, Q11, Q12, Q21, Q22);
  }
#undef ROT

  float w0 = A00, w1 = A11, w2 = A22;
#define CSWAP(wa, wb, qa0, qb0, qa1, qb1, qa2, qb2)                          \
  {                                                                          \
    bool sw = (wb) < (wa);                                                   \
    float tw = wa; wa = sw ? wb : wa; wb = sw ? tw : wb;                     \
    float t0 = qa0; qa0 = sw ? qb0 : qa0; qb0 = sw ? t0 : qb0;               \
    float t1 = qa1; qa1 = sw ? qb1 : qa1; qb1 = sw ? t1 : qb1;               \
    float t2 = qa2; qa2 = sw ? qb2 : qa2; qb2 = sw ? t2 : qb2;               \
  }
  CSWAP(w0, w1, Q00, Q01, Q10, Q11, Q20, Q21);
  CSWAP(w1, w2, Q01, Q02, Q11, Q12, Q21, Q22);
  CSWAP(w0, w1, Q00, Q01, Q10, Q11, Q20, Q21);
#undef CSWAP

  Q[0][0] = Q00; Q[0][1] = Q01; Q[0][2] = Q02;
  Q[1][0] = Q10; Q[1][1] = Q11; Q[1][2] = Q12;
  Q[2][0] = Q20; Q[2][1] = Q21; Q[2][2] = Q22;
}

// ---------------------------------------------------------------------------
// Kernel B: one thread per graph. Centroid/central moments from raw sums,
// Jacobi, serial sign scan (expected ~1 atom), epilogue.
// ---------------------------------------------------------------------------
__global__ __launch_bounds__(64) void eigen_kernel(
    const float* __restrict__ pos, const int* __restrict__ wsi,
    const float* __restrict__ wsf, float* __restrict__ out, int G) {
  int g = (int)(blockIdx.x * (unsigned)blockDim.x + threadIdx.x);
  if (g >= G) return;

  int s = wsi[g];
  int e = wsi[g + 1];
  int cnt = e - s;

  float sx  = wsf[0 * G + g];
  float sy  = wsf[1 * G + g];
  float sz  = wsf[2 * G + g];
  float sxx = wsf[3 * G + g];
  float syy = wsf[4 * G + g];
  float szz = wsf[5 * G + g];
  float sxy = wsf[6 * G + g];
  float sxz = wsf[7 * G + g];
  float syz = wsf[8 * G + g];

  float fn = (float)(cnt > 0 ? cnt : 1);
  float inv = 1.0f / fn;
  float mx = sx * inv, my = sy * inv, mz = sz * inv;
  // central second moments: Sab = sum(ab) - n*ma*mb
  float Sxx = fmaf(-fn * mx, mx, sxx);
  float Syy = fmaf(-fn * my, my, syy);
  float Szz = fmaf(-fn * mz, mz, szz);
  float Sxy = fmaf(-fn * mx, my, sxy);
  float Sxz = fmaf(-fn * mx, mz, sxz);
  float Syz = fmaf(-fn * my, mz, syz);

  // inertia tensor: I = tr(S)*Id - S
  float ixx = Syy + Szz;
  float iyy = Sxx + Szz;
  float izz = Sxx + Syy;
  float ixy = -Sxy;
  float ixz = -Sxz;
  float iyz = -Syz;

  float Q[3][3];
  jacobi3_f32(ixx, iyy, izz, ixy, ixz, iyz, Q);

  float q00 = Q[0][0], q10 = Q[1][0], q20 = Q[2][0];
  float q01 = Q[0][1], q11 = Q[1][1], q21 = Q[2][1];

  // first atom (original order) with |proj| > EPS, axes 0 and 1 independent
  bool found0 = false, found1 = false;
  float v0 = 0.f, v1 = 0.f;
  for (int i = s; i < e; ++i) {
    float x = pos[3 * i + 0] - mx;
    float y = pos[3 * i + 1] - my;
    float z = pos[3 * i + 2] - mz;
    float p0 = x * q00 + y * q10 + z * q20;
    float p1 = x * q01 + y * q11 + z * q21;
    if (!found0 && fabsf(p0) > CANON_EPS) { v0 = p0; found0 = true; }
    if (!found1 && fabsf(p1) > CANON_EPS) { v1 = p1; found1 = true; }
    if (found0 && found1) break;
  }
  float s0 = (found0 && v0 < 0.f) ? -1.f : 1.f;
  float s1 = (found1 && v1 < 0.f) ? -1.f : 1.f;

  float q0x = q00 * s0, q0y = q10 * s0, q0z = q20 * s0;
  float q1x = q01 * s1, q1y = q11 * s1, q1z = q21 * s1;
  float q2x = q0y * q1z - q0z * q1y;
  float q2y = q0z * q1x - q0x * q1z;
  float q2z = q0x * q1y - q0y * q1x;
  float* o = out + (size_t)g * 9;
  o[0] = q0x; o[1] = q1x; o[2] = q2x;
  o[3] = q0y; o[4] = q1y; o[5] = q2y;
  o[6] = q0z; o[7] = q1z; o[8] = q2z;
}

extern "C" void kernel_launch(void* const* d_in, const int* in_sizes, int n_in,
                              void* d_out, int out_size, void* d_ws, size_t ws_size,
                              hipStream_t stream) {
  const float* pos = (const float*)d_in[0];
  const int* batch = (const int*)d_in[1];
  float* out = (float*)d_out;

  int n = in_sizes[0] / 3;  // N atoms
  int G = out_size / 9;     // graphs

  int* wsi = (int*)d_ws;  // (G+1) ints: graph start offsets
  float* wsf = (float*)((char*)d_ws + (((size_t)(G + 1) * 4 + 255) & ~255ull));
  // wsf: 9 * G floats, SoA accumulators

  int totalf = 9 * G;
  zero_ws_kernel<<<(totalf + 255) / 256, 256, 0, stream>>>(wsf, totalf);

  int threadsA = (n + KPT - 1) / KPT;
  moments_kernel<<<(threadsA + 255) / 256, 256, 0, stream>>>(pos, batch, wsi,
                                                             wsf, n, G);

  eigen_kernel<<<(G + 63) / 64, 64, 0, stream>>>(pos, wsi, wsf, out, G);
}

// Round 7
// 22.734 us; speedup vs baseline: 3.0856x; 3.0856x over previous
//
#include <hip/hip_runtime.h>
#include <math.h>

#define CANON_EPS 1e-4f

// ---------------------------------------------------------------------------
// Kernel 1: CSR boundaries from the sorted batch array (streaming scatter,
// no dependent-load chains). Every entry of wsi[0..G] written exactly once.
// ---------------------------------------------------------------------------
__global__ __launch_bounds__(256) void build_starts_kernel(
    const int* __restrict__ batch, int* __restrict__ wsi, int n, int G) {
  int i = (int)(blockIdx.x * (unsigned)blockDim.x + threadIdx.x);
  if (i >= n) return;
  int b = batch[i];
  int bp = (i == 0) ? -1 : batch[i - 1];
  for (int g = bp + 1; g <= b; ++g) wsi[g] = i;
  if (i == n - 1) {
    for (int g = b + 1; g <= G; ++g) wsi[G > g ? g : G] = n;  // fills b+1..G
  }
}

// ---------------------------------------------------------------------------
// Kernel 2: moments. 16 lanes/graph, 4 graphs/wave, 8192 waves total.
// Main body: unroll-5 clamped loads -> 15 loads in flight, ONE waitcnt round
// for graphs up to 80 atoms (>=98% of Poisson-64); loop epilogue for the rest.
// Writes 9 floats/graph SoA: wsf[c*G+g], c=0..8: cx,cy,cz,ixx,iyy,izz,ixy,ixz,iyz.
// ---------------------------------------------------------------------------
__global__ __launch_bounds__(256) void moments_kernel(
    const float* __restrict__ pos, const int* __restrict__ wsi,
    float* __restrict__ wsf, int G) {
  int tid = (int)(blockIdx.x * (unsigned)blockDim.x + threadIdx.x);
  int gid = tid >> 4;
  int sub = tid & 15;
  if (gid >= G) return;

  int s = wsi[gid];
  int e = wsi[gid + 1];
  int cnt = e - s;

  float sx = 0.f, sy = 0.f, sz = 0.f;
  float sxx = 0.f, syy = 0.f, szz = 0.f, sxy = 0.f, sxz = 0.f, syz = 0.f;

  // ---- main: 5 predication-free batched rounds (indices clamped to s) ----
#pragma unroll
  for (int k = 0; k < 5; ++k) {
    int i = s + sub + 16 * k;
    bool in = i < e;
    int ii = in ? i : s;                  // always-valid address
    float m = in ? 1.0f : 0.0f;
    float x = pos[3 * ii + 0] * m;
    float y = pos[3 * ii + 1] * m;
    float z = pos[3 * ii + 2] * m;
    sx += x; sy += y; sz += z;
    sxx = fmaf(x, x, sxx); syy = fmaf(y, y, syy); szz = fmaf(z, z, szz);
    sxy = fmaf(x, y, sxy); sxz = fmaf(x, z, sxz); syz = fmaf(y, z, syz);
  }
  // ---- rare epilogue: graphs with more than 80 atoms ---------------------
  for (int i = s + 80 + sub; i < e; i += 16) {
    float x = pos[3 * i + 0];
    float y = pos[3 * i + 1];
    float z = pos[3 * i + 2];
    sx += x; sy += y; sz += z;
    sxx = fmaf(x, x, sxx); syy = fmaf(y, y, syy); szz = fmaf(z, z, szz);
    sxy = fmaf(x, y, sxy); sxz = fmaf(x, z, sxz); syz = fmaf(y, z, syz);
  }

  // ---- 16-lane butterfly reductions --------------------------------------
#define RED16(v)                                                             \
  v += __shfl_xor(v, 1); v += __shfl_xor(v, 2);                              \
  v += __shfl_xor(v, 4); v += __shfl_xor(v, 8);
  RED16(sx) RED16(sy) RED16(sz)
  RED16(sxx) RED16(syy) RED16(szz)
  RED16(sxy) RED16(sxz) RED16(syz)
#undef RED16

  float fn = (float)(cnt > 0 ? cnt : 1);
  float inv = 1.0f / fn;
  float mx = sx * inv, my = sy * inv, mz = sz * inv;
  // central second moments: Sab = sum(ab) - n*ma*mb
  float Sxx = fmaf(-fn * mx, mx, sxx);
  float Syy = fmaf(-fn * my, my, syy);
  float Szz = fmaf(-fn * mz, mz, szz);
  float Sxy = fmaf(-fn * mx, my, sxy);
  float Sxz = fmaf(-fn * mx, mz, sxz);
  float Syz = fmaf(-fn * my, mz, syz);

  // component select (no runtime indexing); inertia I = tr(S)*Id - S
  float v = mx;                            // sub=0
  v = (sub == 1) ? my : v;
  v = (sub == 2) ? mz : v;
  v = (sub == 3) ? (Syy + Szz) : v;        // ixx
  v = (sub == 4) ? (Sxx + Szz) : v;        // iyy
  v = (sub == 5) ? (Sxx + Syy) : v;        // izz
  v = (sub == 6) ? (-Sxy) : v;             // ixy
  v = (sub == 7) ? (-Sxz) : v;             // ixz
  if (sub < 8) wsf[sub * G + gid] = v;
  if (sub == 0) wsf[8 * G + gid] = -Syz;   // iyz
}

// ---------------------------------------------------------------------------
// Branch-free 3x3 symmetric Jacobi eigensolver in f32, 5 cyclic sweeps.
// Columns of Q = eigenvectors; eigenvalues sorted ascending (matches eigh).
// ---------------------------------------------------------------------------
__device__ __forceinline__ void jacobi3_f32(float a00, float a11, float a22,
                                            float a01, float a02, float a12,
                                            float Q[3][3]) {
  float A00 = a00, A11 = a11, A22 = a22;
  float A01 = a01, A02 = a02, A12 = a12;
  float Q00 = 1.f, Q01 = 0.f, Q02 = 0.f;
  float Q10 = 0.f, Q11 = 1.f, Q12 = 0.f;
  float Q20 = 0.f, Q21 = 0.f, Q22 = 1.f;

#define ROT(App, Aqq, Apq, Akp, Akq, Qrp0, Qrq0, Qrp1, Qrq1, Qrp2, Qrq2)     \
  {                                                                          \
    float apq = Apq;                                                         \
    float theta = (Aqq - App) / (2.0f * apq);                                \
    float t = copysignf(1.0f, theta) /                                       \
              (fabsf(theta) + sqrtf(1.0f + theta * theta));                  \
    t = (apq == 0.0f) ? 0.0f : t; /* kills 0/0 NaN path */                   \
    float c = 1.0f / sqrtf(1.0f + t * t);                                    \
    float s = t * c;                                                         \
    App = App - t * apq;                                                     \
    Aqq = Aqq + t * apq;                                                     \
    Apq = 0.0f;                                                              \
    float akp = Akp, akq = Akq;                                              \
    Akp = c * akp - s * akq;                                                 \
    Akq = s * akp + c * akq;                                                 \
    float r0p = Qrp0, r0q = Qrq0;                                            \
    Qrp0 = c * r0p - s * r0q;                                                \
    Qrq0 = s * r0p + c * r0q;                                                \
    float r1p = Qrp1, r1q = Qrq1;                                            \
    Qrp1 = c * r1p - s * r1q;                                                \
    Qrq1 = s * r1p + c * r1q;                                                \
    float r2p = Qrp2, r2q = Qrq2;                                            \
    Qrp2 = c * r2p - s * r2q;                                                \
    Qrq2 = s * r2p + c * r2q;                                                \
  }

#pragma unroll
  for (int sweep = 0; sweep < 5; ++sweep) {
    ROT(A00, A11, A01, A02, A12, Q00, Q01, Q10, Q11, Q20, Q21);
    ROT(A00, A22, A02, A01, A12, Q00, Q02, Q10, Q12, Q20, Q22);
    ROT(A11, A22, A12, A01, A02, Q01, Q02, Q11, Q12, Q21, Q22);
  }
#undef ROT

  float w0 = A00, w1 = A11, w2 = A22;
#define CSWAP(wa, wb, qa0, qb0, qa1, qb1, qa2, qb2)                          \
  {                                                                          \
    bool sw = (wb) < (wa);                                                   \
    float tw = wa; wa = sw ? wb : wa; wb = sw ? tw : wb;                     \
    float t0 = qa0; qa0 = sw ? qb0 : qa0; qb0 = sw ? t0 : qb0;               \
    float t1 = qa1; qa1 = sw ? qb1 : qa1; qb1 = sw ? t1 : qb1;               \
    float t2 = qa2; qa2 = sw ? qb2 : qa2; qb2 = sw ? t2 : qb2;               \
  }
  CSWAP(w0, w1, Q00, Q01, Q10, Q11, Q20, Q21);
  CSWAP(w1, w2, Q01, Q02, Q11, Q12, Q21, Q22);
  CSWAP(w0, w1, Q00, Q01, Q10, Q11, Q20, Q21);
#undef CSWAP

  Q[0][0] = Q00; Q[0][1] = Q01; Q[0][2] = Q02;
  Q[1][0] = Q10; Q[1][1] = Q11; Q[1][2] = Q12;
  Q[2][0] = Q20; Q[2][1] = Q21; Q[2][2] = Q22;
}

// ---------------------------------------------------------------------------
// Kernel 3: one thread per graph. Jacobi + batched sign scan + epilogue.
// Scan loads 4 atoms per round with clamped indices (one waitcnt round each;
// expected rounds per graph: 1).
// ---------------------------------------------------------------------------
__global__ __launch_bounds__(256) void eigen_kernel(
    const float* __restrict__ pos, const int* __restrict__ wsi,
    const float* __restrict__ wsf, float* __restrict__ out, int G) {
  int g = (int)(blockIdx.x * (unsigned)blockDim.x + threadIdx.x);
  if (g >= G) return;

  int s = wsi[g];
  int e = wsi[g + 1];

  float cx  = wsf[0 * G + g];
  float cy  = wsf[1 * G + g];
  float cz  = wsf[2 * G + g];
  float ixx = wsf[3 * G + g];
  float iyy = wsf[4 * G + g];
  float izz = wsf[5 * G + g];
  float ixy = wsf[6 * G + g];
  float ixz = wsf[7 * G + g];
  float iyz = wsf[8 * G + g];

  float Q[3][3];
  jacobi3_f32(ixx, iyy, izz, ixy, ixz, iyz, Q);

  float q00 = Q[0][0], q10 = Q[1][0], q20 = Q[2][0];
  float q01 = Q[0][1], q11 = Q[1][1], q21 = Q[2][1];

  // first atom (original order) with |proj| > EPS, axes 0 and 1 independent
  bool found0 = false, found1 = false;
  float v0 = 0.f, v1 = 0.f;
  for (int base = s; base < e && !(found0 && found1); base += 4) {
    float px[4], py[4], pz[4];
    bool iv[4];
#pragma unroll
    for (int j = 0; j < 4; ++j) {
      int i = base + j;
      bool in = i < e;
      iv[j] = in;
      int ii = in ? i : s;
      px[j] = pos[3 * ii + 0];
      py[j] = pos[3 * ii + 1];
      pz[j] = pos[3 * ii + 2];
    }
#pragma unroll
    for (int j = 0; j < 4; ++j) {
      if (iv[j]) {
        float x = px[j] - cx, y = py[j] - cy, z = pz[j] - cz;
        float p0 = x * q00 + y * q10 + z * q20;
        float p1 = x * q01 + y * q11 + z * q21;
        if (!found0 && fabsf(p0) > CANON_EPS) { v0 = p0; found0 = true; }
        if (!found1 && fabsf(p1) > CANON_EPS) { v1 = p1; found1 = true; }
      }
    }
  }
  float s0 = (found0 && v0 < 0.f) ? -1.f : 1.f;
  float s1 = (found1 && v1 < 0.f) ? -1.f : 1.f;

  float q0x = q00 * s0, q0y = q10 * s0, q0z = q20 * s0;
  float q1x = q01 * s1, q1y = q11 * s1, q1z = q21 * s1;
  float q2x = q0y * q1z - q0z * q1y;
  float q2y = q0z * q1x - q0x * q1z;
  float q2z = q0x * q1y - q0y * q1x;
  float* o = out + (size_t)g * 9;
  o[0] = q0x; o[1] = q1x; o[2] = q2x;
  o[3] = q0y; o[4] = q1y; o[5] = q2y;
  o[6] = q0z; o[7] = q1z; o[8] = q2z;
}

extern "C" void kernel_launch(void* const* d_in, const int* in_sizes, int n_in,
                              void* d_out, int out_size, void* d_ws, size_t ws_size,
                              hipStream_t stream) {
  const float* pos = (const float*)d_in[0];
  const int* batch = (const int*)d_in[1];
  float* out = (float*)d_out;

  int n = in_sizes[0] / 3;  // N atoms
  int G = out_size / 9;     // graphs

  int* wsi = (int*)d_ws;  // (G+1) ints: graph start offsets
  float* wsf = (float*)((char*)d_ws + (((size_t)(G + 1) * 4 + 255) & ~255ull));
  // wsf: 9 * G floats, SoA

  build_starts_kernel<<<(n + 255) / 256, 256, 0, stream>>>(batch, wsi, n, G);

  // 16 lanes/graph -> 16 graphs per 256-thread block
  moments_kernel<<<(G * 16 + 255) / 256, 256, 0, stream>>>(pos, wsi, wsf, G);

  eigen_kernel<<<(G + 255) / 256, 256, 0, stream>>>(pos, wsi, wsf, out, G);
}

// Round 8
// 21.419 us; speedup vs baseline: 3.2749x; 1.0614x over previous
//
#include <hip/hip_runtime.h>
#include <math.h>

#define CANON_EPS 1e-4f

// ---------------------------------------------------------------------------
// Kernel 1: CSR boundaries from sorted batch. int4-vectorized: 4 atoms/thread.
// Every entry of wsi[0..G] written exactly once (empty graphs included).
// ---------------------------------------------------------------------------
__global__ __launch_bounds__(256) void build_starts_kernel(
    const int* __restrict__ batch, int* __restrict__ wsi, int n, int G) {
  int t = (int)(blockIdx.x * (unsigned)blockDim.x + threadIdx.x);
  int base = t * 4;
  if (base >= n) return;

  int b0, b1, b2, b3;
  if (base + 4 <= n) {
    int4 b4 = *reinterpret_cast<const int4*>(batch + base);
    b0 = b4.x; b1 = b4.y; b2 = b4.z; b3 = b4.w;
  } else {  // tail (n % 4 != 0)
    b0 = batch[base];
    b1 = (base + 1 < n) ? batch[base + 1] : b0;
    b2 = (base + 2 < n) ? batch[base + 2] : b1;
    b3 = (base + 3 < n) ? batch[base + 3] : b2;
  }
  int bp = (base > 0) ? batch[base - 1] : -1;

  int B[4] = {b0, b1, b2, b3};
#pragma unroll
  for (int j = 0; j < 4; ++j) {
    int i = base + j;
    if (i >= n) break;
    int prev = (j == 0) ? bp : B[j - 1];
    int b = B[j];
    for (int g = prev + 1; g <= b; ++g) wsi[g] = i;
    if (i == n - 1) {
      for (int g = b + 1; g <= G; ++g) wsi[g] = n;
    }
  }
}

// ---------------------------------------------------------------------------
// Kernel 2: moments. 16 lanes/graph. Unroll-5 clamped batched loads (15 loads
// in flight -> one waitcnt round for graphs <= 80 atoms; rare epilogue).
// Writes 9 floats/graph AoS: wsf[9*g + c], c: sx-like? NO: c = 0..8 :
// cx,cy,cz,ixx,iyy,izz,ixy,ixz,iyz (centroid + inertia, ready for eigen).
// ---------------------------------------------------------------------------
__global__ __launch_bounds__(256) void moments_kernel(
    const float* __restrict__ pos, const int* __restrict__ wsi,
    float* __restrict__ wsf, int G) {
  int tid = (int)(blockIdx.x * (unsigned)blockDim.x + threadIdx.x);
  int gid = tid >> 4;
  int sub = tid & 15;
  if (gid >= G) return;

  int s = wsi[gid];
  int e = wsi[gid + 1];
  int cnt = e - s;

  float sx = 0.f, sy = 0.f, sz = 0.f;
  float sxx = 0.f, syy = 0.f, szz = 0.f, sxy = 0.f, sxz = 0.f, syz = 0.f;

#pragma unroll
  for (int k = 0; k < 5; ++k) {
    int i = s + sub + 16 * k;
    bool in = i < e;
    int ii = in ? i : 0;                  // always-valid address
    float m = in ? 1.0f : 0.0f;
    float x = pos[3 * ii + 0] * m;
    float y = pos[3 * ii + 1] * m;
    float z = pos[3 * ii + 2] * m;
    sx += x; sy += y; sz += z;
    sxx = fmaf(x, x, sxx); syy = fmaf(y, y, syy); szz = fmaf(z, z, szz);
    sxy = fmaf(x, y, sxy); sxz = fmaf(x, z, sxz); syz = fmaf(y, z, syz);
  }
  for (int i = s + 80 + sub; i < e; i += 16) {  // rare: graphs > 80 atoms
    float x = pos[3 * i + 0];
    float y = pos[3 * i + 1];
    float z = pos[3 * i + 2];
    sx += x; sy += y; sz += z;
    sxx = fmaf(x, x, sxx); syy = fmaf(y, y, szz * 0.f + syy); szz = fmaf(z, z, szz);
    sxy = fmaf(x, y, sxy); sxz = fmaf(x, z, sxz); syz = fmaf(y, z, syz);
  }

#define RED16(v)                                                             \
  v += __shfl_xor(v, 1); v += __shfl_xor(v, 2);                              \
  v += __shfl_xor(v, 4); v += __shfl_xor(v, 8);
  RED16(sx) RED16(sy) RED16(sz)
  RED16(sxx) RED16(syy) RED16(szz)
  RED16(sxy) RED16(sxz) RED16(syz)
#undef RED16

  float fn = (float)(cnt > 0 ? cnt : 1);
  float inv = 1.0f / fn;
  float mx = sx * inv, my = sy * inv, mz = sz * inv;
  float Sxx = fmaf(-fn * mx, mx, sxx);
  float Syy = fmaf(-fn * my, my, syy);
  float Szz = fmaf(-fn * mz, mz, szz);
  float Sxy = fmaf(-fn * mx, my, sxy);
  float Sxz = fmaf(-fn * mx, mz, sxz);
  float Syz = fmaf(-fn * my, mz, syz);

  // component select; inertia I = tr(S)*Id - S
  float v = mx;                            // sub=0
  v = (sub == 1) ? my : v;
  v = (sub == 2) ? mz : v;
  v = (sub == 3) ? (Syy + Szz) : v;        // ixx
  v = (sub == 4) ? (Sxx + Szz) : v;        // iyy
  v = (sub == 5) ? (Sxx + Syy) : v;        // izz
  v = (sub == 6) ? (-Sxy) : v;             // ixy
  v = (sub == 7) ? (-Sxz) : v;             // ixz
  v = (sub == 8) ? (-Syz) : v;             // iyz
  if (sub < 9) wsf[(size_t)gid * 9 + sub] = v;   // AoS: 36 B per graph
}

// ---------------------------------------------------------------------------
// Branch-free 3x3 symmetric Jacobi eigensolver in f32, 4 cyclic sweeps.
// Columns of Q = eigenvectors; eigenvalues sorted ascending (matches eigh).
// ---------------------------------------------------------------------------
__device__ __forceinline__ void jacobi3_f32(float a00, float a11, float a22,
                                            float a01, float a02, float a12,
                                            float Q[3][3]) {
  float A00 = a00, A11 = a11, A22 = a22;
  float A01 = a01, A02 = a02, A12 = a12;
  float Q00 = 1.f, Q01 = 0.f, Q02 = 0.f;
  float Q10 = 0.f, Q11 = 1.f, Q12 = 0.f;
  float Q20 = 0.f, Q21 = 0.f, Q22 = 1.f;

#define ROT(App, Aqq, Apq, Akp, Akq, Qrp0, Qrq0, Qrp1, Qrq1, Qrp2, Qrq2)     \
  {                                                                          \
    float apq = Apq;                                                         \
    float theta = (Aqq - App) / (2.0f * apq);                                \
    float t = copysignf(1.0f, theta) /                                       \
              (fabsf(theta) + sqrtf(1.0f + theta * theta));                  \
    t = (apq == 0.0f) ? 0.0f : t; /* kills 0/0 NaN path */                   \
    float c = 1.0f / sqrtf(1.0f + t * t);                                    \
    float s = t * c;                                                         \
    App = App - t * apq;                                                     \
    Aqq = Aqq + t * apq;                                                     \
    Apq = 0.0f;                                                              \
    float akp = Akp, akq = Akq;                                              \
    Akp = c * akp - s * akq;                                                 \
    Akq = s * akp + c * akq;                                                 \
    float r0p = Qrp0, r0q = Qrq0;                                            \
    Qrp0 = c * r0p - s * r0q;                                                \
    Qrq0 = s * r0p + c * r0q;                                                \
    float r1p = Qrp1, r1q = Qrq1;                                            \
    Qrp1 = c * r1p - s * r1q;                                                \
    Qrq1 = s * r1p + c * r1q;                                                \
    float r2p = Qrp2, r2q = Qrq2;                                            \
    Qrp2 = c * r2p - s * r2q;                                                \
    Qrq2 = s * r2p + c * r2q;                                                \
  }

#pragma unroll
  for (int sweep = 0; sweep < 4; ++sweep) {
    ROT(A00, A11, A01, A02, A12, Q00, Q01, Q10, Q11, Q20, Q21);
    ROT(A00, A22, A02, A01, A12, Q00, Q02, Q10, Q12, Q20, Q22);
    ROT(A11, A22, A12, A01, A02, Q01, Q02, Q11, Q12, Q21, Q22);
  }
#undef ROT

  float w0 = A00, w1 = A11, w2 = A22;
#define CSWAP(wa, wb, qa0, qb0, qa1, qb1, qa2, qb2)                          \
  {                                                                          \
    bool sw = (wb) < (wa);                                                   \
    float tw = wa; wa = sw ? wb : wa; wb = sw ? tw : wb;                     \
    float t0 = qa0; qa0 = sw ? qb0 : qa0; qb0 = sw ? t0 : qb0;               \
    float t1 = qa1; qa1 = sw ? qb1 : qa1; qb1 = sw ? t1 : qb1;               \
    float t2 = qa2; qa2 = sw ? qb2 : qa2; qb2 = sw ? t2 : qb2;               \
  }
  CSWAP(w0, w1, Q00, Q01, Q10, Q11, Q20, Q21);
  CSWAP(w1, w2, Q01, Q02, Q11, Q12, Q21, Q22);
  CSWAP(w0, w1, Q00, Q01, Q10, Q11, Q20, Q21);
#undef CSWAP

  Q[0][0] = Q00; Q[0][1] = Q01; Q[0][2] = Q02;
  Q[1][0] = Q10; Q[1][1] = Q11; Q[1][2] = Q12;
  Q[2][0] = Q20; Q[2][1] = Q21; Q[2][2] = Q22;
}

// ---------------------------------------------------------------------------
// Kernel 3: one thread per graph. Round 1: wsi + 9 AoS moments (1-2 lines).
// Round 2: first-4-atom loads issued BEFORE Jacobi (latency hidden under the
// ~1200-cy Jacobi VALU chain). Sign fixup from preloaded atoms; rare serial
// fallback past atom 4. 64-thread blocks spread 512 blocks across CUs.
// ---------------------------------------------------------------------------
__global__ __launch_bounds__(64) void eigen_kernel(
    const float* __restrict__ pos, const int* __restrict__ wsi,
    const float* __restrict__ wsf, float* __restrict__ out, int G) {
  int g = (int)(blockIdx.x * (unsigned)blockDim.x + threadIdx.x);
  if (g >= G) return;

  int s = wsi[g];
  int e = wsi[g + 1];

  const float* m = wsf + (size_t)g * 9;
  float cx  = m[0];
  float cy  = m[1];
  float cz  = m[2];
  float ixx = m[3];
  float iyy = m[4];
  float izz = m[5];
  float ixy = m[6];
  float ixz = m[7];
  float iyz = m[8];

  // issue first-4-atom loads now; Jacobi below hides their latency
  float px0, py0, pz0, px1, py1, pz1, px2, py2, pz2, px3, py3, pz3;
  {
    int i0 = (s + 0 < e) ? s + 0 : 0;
    int i1 = (s + 1 < e) ? s + 1 : 0;
    int i2 = (s + 2 < e) ? s + 2 : 0;
    int i3 = (s + 3 < e) ? s + 3 : 0;
    px0 = pos[3 * i0 + 0]; py0 = pos[3 * i0 + 1]; pz0 = pos[3 * i0 + 2];
    px1 = pos[3 * i1 + 0]; py1 = pos[3 * i1 + 1]; pz1 = pos[3 * i1 + 2];
    px2 = pos[3 * i2 + 0]; py2 = pos[3 * i2 + 1]; pz2 = pos[3 * i2 + 2];
    px3 = pos[3 * i3 + 0]; py3 = pos[3 * i3 + 1]; pz3 = pos[3 * i3 + 2];
  }

  float Q[3][3];
  jacobi3_f32(ixx, iyy, izz, ixy, ixz, iyz, Q);

  float q00 = Q[0][0], q10 = Q[1][0], q20 = Q[2][0];
  float q01 = Q[0][1], q11 = Q[1][1], q21 = Q[2][1];

  // first atom (original order) with |proj| > EPS, axes 0 and 1 independent
  bool found0 = false, found1 = false;
  float v0 = 0.f, v1 = 0.f;
#define CHECK(PX, PY, PZ, J)                                                 \
  if (s + (J) < e) {                                                         \
    float x = (PX) - cx, y = (PY) - cy, z = (PZ) - cz;                       \
    float p0 = x * q00 + y * q10 + z * q20;                                  \
    float p1 = x * q01 + y * q11 + z * q21;                                  \
    if (!found0 && fabsf(p0) > CANON_EPS) { v0 = p0; found0 = true; }        \
    if (!found1 && fabsf(p1) > CANON_EPS) { v1 = p1; found1 = true; }        \
  }
  CHECK(px0, py0, pz0, 0)
  CHECK(px1, py1, pz1, 1)
  CHECK(px2, py2, pz2, 2)
  CHECK(px3, py3, pz3, 3)
#undef CHECK
  // rare fallback: not decided within the first 4 atoms
  for (int i = s + 4; i < e && !(found0 && found1); ++i) {
    float x = pos[3 * i + 0] - cx;
    float y = pos[3 * i + 1] - cy;
    float z = pos[3 * i + 2] - cz;
    float p0 = x * q00 + y * q10 + z * q20;
    float p1 = x * q01 + y * q11 + z * q21;
    if (!found0 && fabsf(p0) > CANON_EPS) { v0 = p0; found0 = true; }
    if (!found1 && fabsf(p1) > CANON_EPS) { v1 = p1; found1 = true; }
  }
  float s0 = (found0 && v0 < 0.f) ? -1.f : 1.f;
  float s1 = (found1 && v1 < 0.f) ? -1.f : 1.f;

  float q0x = q00 * s0, q0y = q10 * s0, q0z = q20 * s0;
  float q1x = q01 * s1, q1y = q11 * s1, q1z = q21 * s1;
  float q2x = q0y * q1z - q0z * q1y;
  float q2y = q0z * q1x - q0x * q1z;
  float q2z = q0x * q1y - q0y * q1x;
  float* o = out + (size_t)g * 9;
  o[0] = q0x; o[1] = q1x; o[2] = q2x;
  o[3] = q0y; o[4] = q1y; o[5] = q2y;
  o[6] = q0z; o[7] = q1z; o[8] = q2z;
}

extern "C" void kernel_launch(void* const* d_in, const int* in_sizes, int n_in,
                              void* d_out, int out_size, void* d_ws, size_t ws_size,
                              hipStream_t stream) {
  const float* pos = (const float*)d_in[0];
  const int* batch = (const int*)d_in[1];
  float* out = (float*)d_out;

  int n = in_sizes[0] / 3;  // N atoms
  int G = out_size / 9;     // graphs

  int* wsi = (int*)d_ws;  // (G+1) ints: graph start offsets
  float* wsf = (float*)((char*)d_ws + (((size_t)(G + 1) * 4 + 255) & ~255ull));
  // wsf: 9 * G floats, AoS (36 B per graph)

  int t1 = (n + 3) / 4;
  build_starts_kernel<<<(t1 + 255) / 256, 256, 0, stream>>>(batch, wsi, n, G);

  moments_kernel<<<(G * 16 + 255) / 256, 256, 0, stream>>>(pos, wsi, wsf, G);

  eigen_kernel<<<(G + 63) / 64, 64, 0, stream>>>(pos, wsi, wsf, out, G);
}